// Round 13
// baseline (467.143 us; speedup 1.0000x reference)
//
#include <hip/hip_runtime.h>

// Problem constants: S=1024, B=8, E=1024, H=16, HD=64
#define M_TOK 8192   // S*B
#define SEQ   1024
#define NB    8
#define EMB   1024
#define NH    16

typedef float  f32x4 __attribute__((ext_vector_type(4)));
typedef __bf16 bf16x8 __attribute__((ext_vector_type(8)));
typedef unsigned short u16x8 __attribute__((ext_vector_type(8)));
typedef unsigned short u16x4 __attribute__((ext_vector_type(4)));

__device__ __forceinline__ unsigned short f2bf(float f) {
  unsigned int u = __builtin_bit_cast(unsigned int, f);
  return (unsigned short)((u + 0x7fffu + ((u >> 16) & 1u)) >> 16);
}

__device__ __forceinline__ f32x4 mfma_bf16(u16x8 a, u16x8 b, f32x4 c) {
  return __builtin_amdgcn_mfma_f32_16x16x32_bf16(
      __builtin_bit_cast(bf16x8, a), __builtin_bit_cast(bf16x8, b), c, 0, 0, 0);
}

__device__ __forceinline__ void gload_lds16(const void* g, void* l) {
  __builtin_amdgcn_global_load_lds(
      (const __attribute__((address_space(1))) void*)g,
      (__attribute__((address_space(3))) void*)l, 16, 0, 0);
}

// ---------------------------------------------------------------- converts
// Fused convert. Activations -> K-tiled batch-major bf16:
//   act'[k>>5][mp][k&31], mp = b*1024 + s   (one MFMA A-frag = 1KB contiguous)
// Weights -> linear bf16.
__global__ __launch_bounds__(256) void cvt_all(
    const float* __restrict__ aq, const float* __restrict__ aqi,
    const float* __restrict__ ak, const float* __restrict__ aki,
    const float* __restrict__ av, const float* __restrict__ avi,
    const float* __restrict__ wq, const float* __restrict__ wqi,
    const float* __restrict__ wo, const float* __restrict__ woi,
    unsigned short* __restrict__ dq, unsigned short* __restrict__ dqi,
    unsigned short* __restrict__ dk, unsigned short* __restrict__ dki,
    unsigned short* __restrict__ dv, unsigned short* __restrict__ dvi,
    unsigned short* __restrict__ dwq, unsigned short* __restrict__ dwqi,
    unsigned short* __restrict__ dwo, unsigned short* __restrict__ dwoi) {
  int b = blockIdx.x;
  if (b < 12288) {
    int seg = b >> 11, local = b & 2047;
    const float* src = (seg == 0) ? aq : (seg == 1) ? aqi : (seg == 2) ? ak
                       : (seg == 3) ? aki : (seg == 4) ? av : avi;
    unsigned short* dst = (seg == 0) ? dq : (seg == 1) ? dqi : (seg == 2) ? dk
                          : (seg == 3) ? dki : (seg == 4) ? dv : dvi;
    int mp0 = local * 4;                 // 4 consecutive m' (same batch)
    int bidx = mp0 >> 10, s0 = mp0 & 1023;
    int rr = threadIdx.x >> 6, tt = threadIdx.x & 63;
    const float* srow = src + (size_t)((s0 + rr) * 8 + bidx) * 1024 + tt * 16;
    float4 v0 = ((const float4*)srow)[0];
    float4 v1 = ((const float4*)srow)[1];
    float4 v2 = ((const float4*)srow)[2];
    float4 v3 = ((const float4*)srow)[3];
    u16x8 o0 = {f2bf(v0.x), f2bf(v0.y), f2bf(v0.z), f2bf(v0.w),
                f2bf(v1.x), f2bf(v1.y), f2bf(v1.z), f2bf(v1.w)};
    u16x8 o1 = {f2bf(v2.x), f2bf(v2.y), f2bf(v2.z), f2bf(v2.w),
                f2bf(v3.x), f2bf(v3.y), f2bf(v3.z), f2bf(v3.w)};
    unsigned short* d = dst + (size_t)(tt >> 1) * 262144 +
                        (size_t)(mp0 + rr) * 32 + (tt & 1) * 16;
    *(u16x8*)d = o0;
    *(u16x8*)(d + 8) = o1;
  } else {
    int b2 = b - 12288;
    const float* src;
    unsigned short* dst;
    int local;
    if (b2 < 3072) { src = wq; dst = dwq; local = b2; }
    else if (b2 < 6144) { src = wqi; dst = dwqi; local = b2 - 3072; }
    else if (b2 < 7168) { src = wo; dst = dwo; local = b2 - 6144; }
    else { src = woi; dst = dwoi; local = b2 - 7168; }
    size_t off = (size_t)local * 1024 + threadIdx.x * 4;
    float4 v4 = *reinterpret_cast<const float4*>(src + off);
    u16x4 o = {f2bf(v4.x), f2bf(v4.y), f2bf(v4.z), f2bf(v4.w)};
    *reinterpret_cast<u16x4*>(dst + off) = o;
  }
}

// ---------------------------------------------------------------- QKV proj
// 128x128 tile. A-frags direct from K-tiled global (registers, L2-served).
// W DOUBLE-BUFFERED in LDS with counted vmcnt across raw s_barriers (T4):
// W(t+1) loads stay in flight through both barriers; no vmcnt(0) drain.
// XCD swizzle 1536 = 8x192; q2 epilogue folds 1/8 attention scale.
__global__ __launch_bounds__(256, 2) void proj_gemm(
    const unsigned short* __restrict__ qreb, const unsigned short* __restrict__ qimb,
    const unsigned short* __restrict__ kreb, const unsigned short* __restrict__ kimb,
    const unsigned short* __restrict__ vreb, const unsigned short* __restrict__ vimb,
    const unsigned short* __restrict__ wr, const unsigned short* __restrict__ wi,
    const float* __restrict__ br, const float* __restrict__ bi,
    unsigned short* __restrict__ q2, unsigned short* __restrict__ k2,
    unsigned short* __restrict__ vt) {
  __shared__ __align__(16) unsigned short smem[18432];  // 36864 B pool
  // K-loop: W dbuf = smem + cur*8192 (2 x 16KB).  Epilogue reuses pool.
  unsigned short (*sC)[140]  = (unsigned short (*)[140])(smem);
  unsigned short (*sCt)[144] = (unsigned short (*)[144])(smem);

  const int tid = threadIdx.x;
  const int lane = tid & 63;
  const int w = tid >> 6;
  const int lr = lane & 15, lk = lane >> 4;
  const int wm = (w & 1) * 64, wn = (w >> 1) * 64;

  // XCD-aware bijective work swizzle: 1536 blocks = 8 XCD x 192
  const int lin = blockIdx.x + blockIdx.y * 24;
  const int wg = (lin & 7) * 192 + (lin >> 3);
  const int n0 = (wg % 24) * 128;
  const int mt = wg / 24;
  const int sec = n0 >> 10;
  const int bb = mt >> 3;            // batch (batch-major m')
  const int ss0 = (mt & 7) * 128;    // s-offset
  const int h_base = (n0 & 1023) >> 6;

  const unsigned short* aRe = (sec == 0) ? qreb : ((sec == 1) ? kreb : vreb);
  const unsigned short* aIm = (sec == 0) ? qimb : ((sec == 1) ? kimb : vimb);

  // W staging indices (granule gid = c*256+tid; row = gid>>3; g = gid&7)
  int srow[4], sgsw[4];
  for (int c = 0; c < 4; ++c) {
    int gid = c * 256 + tid;
    srow[c] = gid >> 3;
    sgsw[c] = (gid & 7) ^ (srow[c] & 7);
  }

  // A-frag offset in tiled layout: frag(mi) = 1KB contiguous block
  const unsigned int aoff = (unsigned int)((mt * 128 + wm + lr) * 32 + lk * 8);

  f32x4 accre[4][4], accim[4][4];
  for (int i = 0; i < 4; ++i)
    for (int j = 0; j < 4; ++j) {
      accre[i][j] = {0.f, 0.f, 0.f, 0.f};
      accim[i][j] = {0.f, 0.f, 0.f, 0.f};
    }
  const u16x8 sign8 = {0x8000, 0x8000, 0x8000, 0x8000, 0x8000, 0x8000, 0x8000, 0x8000};

  // prologue: stage W(0) into buf0, full drain once
#pragma unroll
  for (int c = 0; c < 4; ++c) {
    int row = srow[c], gsw = sgsw[c];
    int kcol = (gsw & 3) * 8;
    size_t woff = (size_t)(n0 + row) * 1024 + kcol;
    gload_lds16((gsw < 4 ? wr : wi) + woff, smem + (c * 256 + w * 64) * 8);
  }
  asm volatile("s_waitcnt vmcnt(0)" ::: "memory");
  __builtin_amdgcn_s_barrier();

#pragma unroll 1
  for (int t = 0; t < 32; ++t) {
    const int cur = t & 1;
    // A fragment loads (compiler-tracked; latency hides under barrier+reads)
    const unsigned short* paR = aRe + (size_t)t * 262144;
    const unsigned short* paI = aIm + (size_t)t * 262144;
    u16x8 ar_[4], ai_[4];
#pragma unroll
    for (int mi = 0; mi < 4; ++mi) {
      ar_[mi] = *(const u16x8*)(paR + aoff + mi * 512);
      ai_[mi] = *(const u16x8*)(paI + aoff + mi * 512);
    }
    // stage W(t+1) into the other buffer; counted wait completes W(t) only
    if (t < 31) {
#pragma unroll
      for (int c = 0; c < 4; ++c) {
        int row = srow[c], gsw = sgsw[c];
        int kcol = (t + 1) * 32 + (gsw & 3) * 8;
        size_t woff = (size_t)(n0 + row) * 1024 + kcol;
        gload_lds16((gsw < 4 ? wr : wi) + woff,
                    smem + (cur ^ 1) * 8192 + (c * 256 + w * 64) * 8);
      }
      asm volatile("s_waitcnt vmcnt(12)" ::: "memory");
    } else {
      asm volatile("s_waitcnt vmcnt(8)" ::: "memory");
    }
    __builtin_amdgcn_s_barrier();
    __builtin_amdgcn_sched_barrier(0);

    const unsigned short* bufc = smem + cur * 8192;
    u16x8 fWr[4], fWi[4];
#pragma unroll
    for (int ni = 0; ni < 4; ++ni) {
      int R = wn + ni * 16 + lr, sw = R & 7;
      fWr[ni] = *(const u16x8*)(bufc + R * 64 + (lk ^ sw) * 8);
      fWi[ni] = *(const u16x8*)(bufc + R * 64 + ((4 + lk) ^ sw) * 8);
    }
    __builtin_amdgcn_s_setprio(1);
#pragma unroll
    for (int mi = 0; mi < 4; ++mi) {
      u16x8 nai = ai_[mi] ^ sign8;
#pragma unroll
      for (int ni = 0; ni < 4; ++ni) {
        accre[mi][ni] = mfma_bf16(ar_[mi], fWr[ni], accre[mi][ni]);
        accre[mi][ni] = mfma_bf16(nai, fWi[ni], accre[mi][ni]);
        accim[mi][ni] = mfma_bf16(ar_[mi], fWi[ni], accim[mi][ni]);
        accim[mi][ni] = mfma_bf16(ai_[mi], fWr[ni], accim[mi][ni]);
      }
    }
    __builtin_amdgcn_s_setprio(0);
    __builtin_amdgcn_s_barrier();   // gates next iter's stage into buf[cur]
  }

  float vbr[4], vbi[4];
  for (int ni = 0; ni < 4; ++ni) {
    int nabs = n0 + wn + ni * 16 + lr;
    vbr[ni] = br[nabs];
    vbi[ni] = bi[nabs];
  }
  // fold attention scale into q (exact: power-of-2 exponent shift)
  const float oscale = (sec == 0) ? 0.125f : 1.0f;

  if (sec < 2) {
    unsigned short* dst = (sec == 0) ? q2 : k2;
#define QK_PASS(ACC, BV, POFF)                                                  \
    for (int ni = 0; ni < 4; ++ni)                                              \
      for (int mi = 0; mi < 4; ++mi)                                            \
        for (int r = 0; r < 4; ++r)                                             \
          sC[wm + mi * 16 + lk * 4 + r][wn + ni * 16 + lr] =                    \
              f2bf((ACC[mi][ni][r] + BV[ni]) * oscale);                         \
    __syncthreads();                                                            \
    for (int it = 0; it < 8; ++it) {                                            \
      int c = it * 256 + tid;                                                   \
      int m = c >> 4, sub = c & 15, h_i = sub >> 3, d8 = sub & 7;               \
      u16x8 v = *(const u16x8*)&sC[m][h_i * 64 + d8 * 8];                       \
      size_t addr = ((size_t)((bb * 16 + h_base + h_i) * 1024 + ss0 + m)) * 128 \
                    + POFF + d8 * 8;                                            \
      *(u16x8*)(dst + addr) = v;                                                \
    }                                                                           \
    __syncthreads();
    QK_PASS(accre, vbr, 0)
    QK_PASS(accim, vbi, 64)
#undef QK_PASS
  } else {
#define VT_PASS(ACC, BV, POFF)                                                  \
    for (int ni = 0; ni < 4; ++ni)                                              \
      for (int mi = 0; mi < 4; ++mi)                                            \
        for (int r = 0; r < 4; ++r)                                             \
          sCt[wn + ni * 16 + lr][wm + mi * 16 + lk * 4 + r] =                   \
              f2bf(ACC[mi][ni][r] + BV[ni]);                                    \
    __syncthreads();                                                            \
    for (int it = 0; it < 8; ++it) {                                            \
      int c = it * 256 + tid;                                                   \
      int nl = c >> 4, sub = c & 15;                                            \
      int h_i = nl >> 6, d = nl & 63;                                           \
      u16x8 v = *(const u16x8*)&sCt[nl][sub * 8];                               \
      size_t addr = ((size_t)(bb * 16 + h_base + h_i) * 128 + d + POFF) * 1024  \
                    + ss0 + sub * 8;                                            \
      *(u16x8*)(vt + addr) = v;                                                 \
    }                                                                           \
    __syncthreads();
    VT_PASS(accre, vbr, 0)
    VT_PASS(accim, vbi, 64)
#undef VT_PASS
  }
}

// ---------------------------------------------------------------- attention
// (r12 proven) 1D grid 1024, XCD-locality. QBLK=128: 4 waves x 32 q-rows.
// Q in registers (pre-scaled 1/8); single-buffer K/V; XOR-swizzled tiles;
// defer-max softmax (THR=8); K-fragments shared across both q-row groups.
__global__ __launch_bounds__(256, 2) void attn_kernel(
    const unsigned short* __restrict__ q2, const unsigned short* __restrict__ k2,
    const unsigned short* __restrict__ vt,
    unsigned short* __restrict__ aor, unsigned short* __restrict__ aoi) {
  __shared__ unsigned short sK[64][128];    // 16 KB
  __shared__ unsigned short sV[128][64];    // 16 KB
  __shared__ unsigned short sP[4][32][72];  // 18 KB, +8 pad

  const int tid = threadIdx.x, lane = tid & 63, w = tid >> 6;
  const int lr = lane & 15, lk = lane >> 4;
  const int lin = blockIdx.x;
  const int idx = lin >> 3;                    // 0..127
  const int bh = (lin & 7) * 16 + (idx >> 3);  // XCD-local bh
  const int q0 = (idx & 7) * 128;
  const int bb = bh >> 4, hh = bh & 15;

  const unsigned short* kbase = k2 + (size_t)bh * 131072;
  const unsigned short* vbase = vt + (size_t)bh * 131072;

  // Q fragments in registers (32 VGPRs), read once
  u16x8 qf[2][4];
#pragma unroll
  for (int fi = 0; fi < 2; ++fi) {
    int row = q0 + w * 32 + fi * 16 + lr;
#pragma unroll
    for (int ks = 0; ks < 4; ++ks)
      qf[fi][ks] = *(const u16x8*)(q2 + (size_t)bh * 131072 + (size_t)row * 128 +
                                   ks * 32 + lk * 8);
  }

  f32x4 o[2][8];
#pragma unroll
  for (int fi = 0; fi < 2; ++fi)
#pragma unroll
    for (int i = 0; i < 8; ++i) o[fi][i] = {0.f, 0.f, 0.f, 0.f};
  float mrun[2][4], lrun[2][4];
#pragma unroll
  for (int fi = 0; fi < 2; ++fi)
#pragma unroll
    for (int r = 0; r < 4; ++r) {
      mrun[fi][r] = -1e30f;
      lrun[fi][r] = 0.f;
    }

#pragma unroll 1
  for (int t0 = 0; t0 < 1024; t0 += 64) {
    // stage K tile (64 x 128), swizzled source
    const unsigned short* kb = kbase + (size_t)t0 * 128;
#pragma unroll
    for (int c = 0; c < 4; ++c) {
      int rb = (w * 4 + c) * 4;
      int row = rb + (lane >> 4);
      int blk = (lane & 15) ^ (row & 7);
      gload_lds16(kb + (size_t)row * 128 + blk * 8, &sK[rb][0]);
    }
    // stage V tile (128 x 64), swizzled source
    const unsigned short* vb = vbase + t0;
#pragma unroll
    for (int c = 0; c < 4; ++c) {
      int rb = (w * 4 + c) * 8;
      int row = rb + (lane >> 3);
      int blk = (lane & 7) ^ (row & 7);
      gload_lds16(vb + (size_t)row * 1024 + blk * 8, &sV[rb][0]);
    }
    __syncthreads();

    // QK^T for BOTH q-row groups, each K-fragment read once
    f32x4 sc[2][4];
#pragma unroll
    for (int fi = 0; fi < 2; ++fi)
#pragma unroll
      for (int nj = 0; nj < 4; ++nj) sc[fi][nj] = {0.f, 0.f, 0.f, 0.f};
    __builtin_amdgcn_s_setprio(1);
#pragma unroll
    for (int ks = 0; ks < 4; ++ks) {
#pragma unroll
      for (int nj = 0; nj < 4; ++nj) {
        int krow = nj * 16 + lr;
        u16x8 kf = *(const u16x8*)&sK[krow][((ks * 4 + lk) ^ (krow & 7)) * 8];
        sc[0][nj] = mfma_bf16(qf[0][ks], kf, sc[0][nj]);
        sc[1][nj] = mfma_bf16(qf[1][ks], kf, sc[1][nj]);
      }
    }
    __builtin_amdgcn_s_setprio(0);

#pragma unroll
    for (int fi = 0; fi < 2; ++fi) {
      // tile max per row + defer decision
      float pmx[4];
      bool need = false;
#pragma unroll
      for (int r = 0; r < 4; ++r) {
        float mx = fmaxf(fmaxf(sc[fi][0][r], sc[fi][1][r]),
                         fmaxf(sc[fi][2][r], sc[fi][3][r]));
        for (int msk = 1; msk < 16; msk <<= 1) mx = fmaxf(mx, __shfl_xor(mx, msk));
        pmx[r] = mx;
        need = need || (mx > mrun[fi][r] + 8.0f);
      }

      if (__any(need)) {
#pragma unroll
        for (int r = 0; r < 4; ++r) {
          float mnew = fmaxf(mrun[fi][r], pmx[r]);
          float corr = __expf(mrun[fi][r] - mnew);
          float p0 = __expf(sc[fi][0][r] - mnew), p1 = __expf(sc[fi][1][r] - mnew);
          float p2 = __expf(sc[fi][2][r] - mnew), p3 = __expf(sc[fi][3][r] - mnew);
          float rs = p0 + p1 + p2 + p3;
          for (int msk = 1; msk < 16; msk <<= 1) rs += __shfl_xor(rs, msk);
          lrun[fi][r] = lrun[fi][r] * corr + rs;
          mrun[fi][r] = mnew;
#pragma unroll
          for (int ni = 0; ni < 8; ++ni) o[fi][ni][r] *= corr;
          int prow = fi * 16 + lk * 4 + r;
          sP[w][prow][0 * 16 + lr] = f2bf(p0);
          sP[w][prow][1 * 16 + lr] = f2bf(p1);
          sP[w][prow][2 * 16 + lr] = f2bf(p2);
          sP[w][prow][3 * 16 + lr] = f2bf(p3);
        }
      } else {
#pragma unroll
        for (int r = 0; r < 4; ++r) {
          float m = mrun[fi][r];
          float p0 = __expf(sc[fi][0][r] - m), p1 = __expf(sc[fi][1][r] - m);
          float p2 = __expf(sc[fi][2][r] - m), p3 = __expf(sc[fi][3][r] - m);
          float rs = p0 + p1 + p2 + p3;
          for (int msk = 1; msk < 16; msk <<= 1) rs += __shfl_xor(rs, msk);
          lrun[fi][r] += rs;
          int prow = fi * 16 + lk * 4 + r;
          sP[w][prow][0 * 16 + lr] = f2bf(p0);
          sP[w][prow][1 * 16 + lr] = f2bf(p1);
          sP[w][prow][2 * 16 + lr] = f2bf(p2);
          sP[w][prow][3 * 16 + lr] = f2bf(p3);
        }
      }
    }

    // PV: O[s, dd] += P[s, t] * VT[dd, t]  (V fragments shared across fi)
    __builtin_amdgcn_s_setprio(1);
#pragma unroll
    for (int ks = 0; ks < 2; ++ks) {
      u16x8 pf0 = *(const u16x8*)&sP[w][lr][ks * 32 + lk * 8];
      u16x8 pf1 = *(const u16x8*)&sP[w][16 + lr][ks * 32 + lk * 8];
#pragma unroll
      for (int ni = 0; ni < 8; ++ni) {
        int vrow = ni * 16 + lr;
        u16x8 vf = *(const u16x8*)&sV[vrow][((ks * 4 + lk) ^ (vrow & 7)) * 8];
        o[0][ni] = mfma_bf16(pf0, vf, o[0][ni]);
        o[1][ni] = mfma_bf16(pf1, vf, o[1][ni]);
      }
    }
    __builtin_amdgcn_s_setprio(0);
    __syncthreads();
  }

#pragma unroll
  for (int fi = 0; fi < 2; ++fi)
#pragma unroll
    for (int r = 0; r < 4; ++r) {
      float inv = 1.0f / lrun[fi][r];
#pragma unroll
      for (int ni = 0; ni < 8; ++ni) o[fi][ni][r] *= inv;
    }
#pragma unroll
  for (int fi = 0; fi < 2; ++fi)
#pragma unroll
    for (int ni = 0; ni < 8; ++ni) {
      int dd = ni * 16 + lr;
#pragma unroll
      for (int r = 0; r < 4; ++r) {
        int sg = q0 + w * 32 + fi * 16 + lk * 4 + r;
        size_t tok = (size_t)sg * 8 + bb;
        if (dd < 64)
          aor[tok * 1024 + hh * 64 + dd] = f2bf(o[fi][ni][r]);
        else
          aoi[tok * 1024 + hh * 64 + (dd - 64)] = f2bf(o[fi][ni][r]);
      }
    }
}

// ---------------------------------------------------------------- out proj
// A+W double-buffered in LDS (2 x 32KB) with counted vmcnt across raw
// barriers (same T4 ledger as proj). XOR-swizzled tiles; XCD swizzle.
__global__ __launch_bounds__(256, 2) void out_gemm(
    const unsigned short* __restrict__ ar, const unsigned short* __restrict__ ai,
    const unsigned short* __restrict__ wr, const unsigned short* __restrict__ wi,
    const float* __restrict__ br, const float* __restrict__ bi,
    float* __restrict__ out) {
  __shared__ __align__(16) unsigned short smem[32768];  // 64 KB: 2 bufs

  const int tid = threadIdx.x;
  const int lane = tid & 63;
  const int w = tid >> 6;
  const int lr = lane & 15, lk = lane >> 4;
  const int wm = (w & 1) * 64, wn = (w >> 1) * 64;

  const int lin = blockIdx.x;
  const int wg = (lin & 7) * 64 + (lin >> 3);
  const int n0 = (wg & 7) * 128;
  const int m0 = (wg >> 3) * 128;

  int srow[4], sgsw[4];
  for (int c = 0; c < 4; ++c) {
    int gid = c * 256 + tid;
    srow[c] = gid >> 3;
    sgsw[c] = (gid & 7) ^ (srow[c] & 7);
  }

  f32x4 accre[4][4], accim[4][4];
  for (int i = 0; i < 4; ++i)
    for (int j = 0; j < 4; ++j) {
      accre[i][j] = {0.f, 0.f, 0.f, 0.f};
      accim[i][j] = {0.f, 0.f, 0.f, 0.f};
    }
  const u16x8 sign8 = {0x8000, 0x8000, 0x8000, 0x8000, 0x8000, 0x8000, 0x8000, 0x8000};

#define OG_STAGE(T1, CB)                                                        \
  do {                                                                          \
    for (int c = 0; c < 4; ++c) {                                               \
      int row = srow[c], gsw = sgsw[c];                                         \
      int kcol = (T1) * 32 + (gsw & 3) * 8;                                     \
      size_t aoff = (size_t)(m0 + row) * 1024 + kcol;                           \
      gload_lds16((gsw < 4 ? ar : ai) + aoff,                                   \
                  smem + (CB) * 16384 + (c * 256 + w * 64) * 8);                \
      size_t woff = (size_t)(n0 + row) * 1024 + kcol;                           \
      gload_lds16((gsw < 4 ? wr : wi) + woff,                                   \
                  smem + (CB) * 16384 + 8192 + (c * 256 + w * 64) * 8);         \
    }                                                                           \
  } while (0)

  // prologue
  OG_STAGE(0, 0);
  asm volatile("s_waitcnt vmcnt(0)" ::: "memory");
  __builtin_amdgcn_s_barrier();

#pragma unroll 1
  for (int t = 0; t < 32; ++t) {
    const int cur = t & 1;
    if (t < 31) {
      OG_STAGE(t + 1, cur ^ 1);
      asm volatile("s_waitcnt vmcnt(8)" ::: "memory");
    } else {
      asm volatile("s_waitcnt vmcnt(0)" ::: "memory");
    }
    __builtin_amdgcn_s_barrier();
    __builtin_amdgcn_sched_barrier(0);

    const unsigned short* bufA = smem + cur * 16384;
    const unsigned short* bufW = bufA + 8192;
    u16x8 fWr[4], fWi[4];
#pragma unroll
    for (int ni = 0; ni < 4; ++ni) {
      int R = wn + ni * 16 + lr, sw = R & 7;
      fWr[ni] = *(const u16x8*)(bufW + R * 64 + (lk ^ sw) * 8);
      fWi[ni] = *(const u16x8*)(bufW + R * 64 + ((4 + lk) ^ sw) * 8);
    }
    __builtin_amdgcn_s_setprio(1);
#pragma unroll
    for (int mi = 0; mi < 4; ++mi) {
      int R = wm + mi * 16 + lr, sw = R & 7;
      u16x8 a_r = *(const u16x8*)(bufA + R * 64 + (lk ^ sw) * 8);
      u16x8 a_i = *(const u16x8*)(bufA + R * 64 + ((4 + lk) ^ sw) * 8);
      u16x8 na_i = a_i ^ sign8;
#pragma unroll
      for (int ni = 0; ni < 4; ++ni) {
        accre[mi][ni] = mfma_bf16(a_r, fWr[ni], accre[mi][ni]);
        accre[mi][ni] = mfma_bf16(na_i, fWi[ni], accre[mi][ni]);
        accim[mi][ni] = mfma_bf16(a_r, fWi[ni], accim[mi][ni]);
        accim[mi][ni] = mfma_bf16(a_i, fWr[ni], accim[mi][ni]);
      }
    }
    __builtin_amdgcn_s_setprio(0);
    __builtin_amdgcn_s_barrier();   // gates next iter's stage into buf[cur]
  }
#undef OG_STAGE

  for (int ni = 0; ni < 4; ++ni) {
    int n = n0 + wn + ni * 16 + lr;
    float vbr = br[n], vbi = bi[n];
    for (int mi = 0; mi < 4; ++mi) {
      for (int r = 0; r < 4; ++r) {
        int m = m0 + wm + mi * 16 + lk * 4 + r;
        out[(size_t)m * 1024 + n] = accre[mi][ni][r] + vbr;
        out[8388608 + (size_t)m * 1024 + n] = accim[mi][ni][r] + vbi;
      }
    }
  }
}

// ---------------------------------------------------------------- launch
extern "C" void kernel_launch(void* const* d_in, const int* in_sizes, int n_in,
                              void* d_out, int out_size, void* d_ws, size_t ws_size,
                              hipStream_t stream) {
  const float* qre = (const float*)d_in[0];
  const float* qim = (const float*)d_in[1];
  const float* kre = (const float*)d_in[2];
  const float* kim = (const float*)d_in[3];
  const float* vre = (const float*)d_in[4];
  const float* vim = (const float*)d_in[5];
  const float* wqkv_re = (const float*)d_in[6];
  const float* wqkv_im = (const float*)d_in[7];
  const float* bqr = (const float*)d_in[8];
  const float* bqi = (const float*)d_in[9];
  const float* wo_re = (const float*)d_in[10];
  const float* wo_im = (const float*)d_in[11];
  const float* bor = (const float*)d_in[12];
  const float* boi = (const float*)d_in[13];

  char* ws = (char*)d_ws;
  unsigned short* wr_bf  = (unsigned short*)(ws + 0);          //  6.29 MB
  unsigned short* wi_bf  = (unsigned short*)(ws + 6291456);
  unsigned short* wor_bf = (unsigned short*)(ws + 12582912);
  unsigned short* woi_bf = (unsigned short*)(ws + 14680064);
  // activation bf16, K-tiled batch-major (dead after proj_gemm)
  unsigned short* qreb   = (unsigned short*)(ws + 16777216);
  unsigned short* qimb   = (unsigned short*)(ws + 33554432);
  unsigned short* kreb   = (unsigned short*)(ws + 50331648);
  unsigned short* kimb   = (unsigned short*)(ws + 67108864);
  unsigned short* vreb   = (unsigned short*)(ws + 83886080);
  unsigned short* vimb   = (unsigned short*)(ws + 100663296);
  unsigned short* q2     = (unsigned short*)(ws + 117440512);  // 33.55 MB
  unsigned short* k2     = (unsigned short*)(ws + 150994944);
  unsigned short* vt     = (unsigned short*)(ws + 184549376);  // end 218.1 MB
  // attn outputs alias the dead activation region
  unsigned short* aor    = (unsigned short*)(ws + 16777216);
  unsigned short* aoi    = (unsigned short*)(ws + 33554432);

  cvt_all<<<20480, 256, 0, stream>>>(qre, qim, kre, kim, vre, vim,
                                     wqkv_re, wqkv_im, wo_re, wo_im,
                                     qreb, qimb, kreb, kimb, vreb, vimb,
                                     wr_bf, wi_bf, wor_bf, woi_bf);

  proj_gemm<<<dim3(24, 64), 256, 0, stream>>>(qreb, qimb, kreb, kimb, vreb, vimb,
                                              wr_bf, wi_bf, bqr, bqi, q2, k2, vt);
  attn_kernel<<<1024, 256, 0, stream>>>(q2, k2, vt, aor, aoi);
  out_gemm<<<512, 256, 0, stream>>>(aor, aoi, wor_bf, woi_bf, bor, boi,
                                    (float*)d_out);
}